// Round 5
// baseline (295.888 us; speedup 1.0000x reference)
//
#include <hip/hip_runtime.h>
#include <math.h>

#define N_NODES 100000
#define N_EDGES 1600000
#define EPS_    1e-5f

// R13: de-confound and fix the two suspected elephants behind the ~160us of
// un-profiled time (R12: total 275, gather 101, dinv ~5):
//  (a) bin_scatter had 98 blocks (62% of CUs idle) + 76K global atomics.
//      Replaced by a 3-pass deterministic counting sort with ZERO global
//      atomics: hist -> per-bucket exclusive scan -> rank scatter.
//  (b) lin re-fetched Wg as 4096 scalar uniform loads per wave. Now float4
//      reads + 2 nodes/lane (M=2) -> 1024 uniform load ops per 128 nodes.
// Five separately-named kernels so the next profile attributes everything.

#define NBKT     782        // ceil(N/128) dst-buckets of 128 nodes
#define BKT_CAP  3072       // mean 2048, +22 sigma -- unreachable
#define PAD_L    64         // per-node ELL capacity (P(Poisson(16)>=64)~1e-20)

#define NB_SORT  391        // sort blocks
#define EPB      4096       // 391*4096 = 1,601,536 >= E
#define SCAN_PAD 512        // next pow2 >= NB_SORT

#define LIN_CHUNKS 782      // 128 nodes per chunk (2 per lane)
#define NB_LIN   391        // x2 waves per block = 782 chunks

// ---- bf16 helpers (raw ushort storage, RNE on pack) -----------------------
__device__ __forceinline__ float bf2f(unsigned short u) {
    union { unsigned int i; float f; } v; v.i = (unsigned int)u << 16; return v.f;
}
__device__ __forceinline__ unsigned short f2bf(float f) {
    union { float f; unsigned int i; } v; v.f = f;
    unsigned int b = v.i + 0x7FFFu + ((v.i >> 16) & 1u);   // round-to-nearest-even
    return (unsigned short)(b >> 16);
}

// ---------------------------------------------------------------------------
// Sort pass 1: per-block LDS histogram over 782 buckets -> coalesced row write
// ---------------------------------------------------------------------------
__global__ void hist_kernel(const int* __restrict__ dst,
                            int* __restrict__ blkHist)
{
    __shared__ int hist[NBKT];
    const int tl = threadIdx.x;
    const int e0 = blockIdx.x * EPB;
    const int ne = min(EPB, N_EDGES - e0);

    for (int i = tl; i < NBKT; i += 256) hist[i] = 0;
    __syncthreads();

    for (int i = tl; i < ne; i += 256)
        atomicAdd(&hist[dst[e0 + i] >> 7], 1);
    __syncthreads();

    int* __restrict__ row = blkHist + (size_t)blockIdx.x * NBKT;
    for (int i = tl; i < NBKT; i += 256) row[i] = hist[i];
}

// ---------------------------------------------------------------------------
// Sort pass 2: one block per bucket j. Exclusive prefix over the NB_SORT
// per-block counts (in block order), written back in place; total -> bktTot.
// ---------------------------------------------------------------------------
__global__ void scan_kernel(int* __restrict__ blkHist,
                            int* __restrict__ bktTot)
{
    __shared__ int col[SCAN_PAD];
    __shared__ int wsum[256];
    const int tl = threadIdx.x;
    const int j  = blockIdx.x;

    for (int b = tl; b < SCAN_PAD; b += 256)
        col[b] = (b < NB_SORT) ? blkHist[(size_t)b * NBKT + j] : 0;
    __syncthreads();

    const int q  = tl * 2;
    const int a0 = col[q], a1 = col[q + 1];
    const int ts = a0 + a1;
    wsum[tl] = ts;
    __syncthreads();

    for (int off = 1; off < 256; off <<= 1) {
        const int v = (tl >= off) ? wsum[tl - off] : 0;
        __syncthreads();
        wsum[tl] += v;
        __syncthreads();
    }
    const int excl = wsum[tl] - ts;
    col[q]     = excl;
    col[q + 1] = excl + a0;
    __syncthreads();

    for (int b = tl; b < NB_SORT; b += 256)
        blkHist[(size_t)b * NBKT + j] = col[b];
    if (tl == 0) bktTot[j] = wsum[255];
}

// ---------------------------------------------------------------------------
// Sort pass 3: rank scatter. Base row (coalesced) + LDS rank counters give a
// unique deterministic slot per edge -- no global atomics.
// ---------------------------------------------------------------------------
__global__ void scatter_kernel(const int* __restrict__ src,
                               const int* __restrict__ dst,
                               const int* __restrict__ blkHist,
                               int* __restrict__ bkt)
{
    __shared__ int sbase[NBKT];
    __shared__ int srank[NBKT];
    const int tl = threadIdx.x;

    const int* __restrict__ row = blkHist + (size_t)blockIdx.x * NBKT;
    for (int i = tl; i < NBKT; i += 256) { sbase[i] = row[i]; srank[i] = 0; }
    __syncthreads();

    const int e0 = blockIdx.x * EPB;
    const int ne = min(EPB, N_EDGES - e0);
    for (int i = tl; i < ne; i += 256) {
        const int d = dst[e0 + i];
        const int s = src[e0 + i];
        const int b = d >> 7;
        const int r = sbase[b] + atomicAdd(&srank[b], 1);
        if (r < BKT_CAP)
            bkt[(size_t)b * BKT_CAP + r] = (s << 7) | (d & 127);
    }
}

// ---------------------------------------------------------------------------
// lin: lane = node, 2 nodes per lane (A/B), acc in VGPRs, Wg read as float4
// wave-uniform loads (1024 load ops per 128 nodes instead of 8192 scalar).
// hb_g stored UNSCALED (dinv folded per edge in gather).
// ---------------------------------------------------------------------------
__global__ void lin_kernel(const float* __restrict__ x,
                           const float* __restrict__ W1,
                           const float* __restrict__ b1,
                           const float* __restrict__ Wg,
                           unsigned short* __restrict__ hb_g)
{
    const int tl    = threadIdx.x;            // 128 threads = 2 waves
    const int chunk = blockIdx.x * 2 + (tl >> 6);
    if (chunk >= LIN_CHUNKS) return;

    const int lane = tl & 63;
    const int nA   = chunk * 128 + lane;
    const int nB   = nA + 64;
    const bool actA = (nA < N_NODES);
    const bool actB = (nB < N_NODES);

    float xA0 = 0.f, xA1 = 0.f, xA2 = 0.f, xB0 = 0.f, xB1 = 0.f, xB2 = 0.f;
    if (actA) { xA0 = x[nA * 3]; xA1 = x[nA * 3 + 1]; xA2 = x[nA * 3 + 2]; }
    if (actB) { xB0 = x[nB * 3]; xB1 = x[nB * 3 + 1]; xB2 = x[nB * 3 + 2]; }

    float accA[64], accB[64];
#pragma unroll
    for (int c = 0; c < 64; ++c) { accA[c] = 0.f; accB[c] = 0.f; }

    for (int k = 0; k < 64; ++k) {
        const float w0 = W1[k];                // wave-uniform
        const float w1 = W1[64 + k];
        const float w2 = W1[128 + k];
        const float bb = b1[k];
        float hA = fmaf(xA0, w0, fmaf(xA1, w1, fmaf(xA2, w2, bb)));
        float hB = fmaf(xB0, w0, fmaf(xB1, w1, fmaf(xB2, w2, bb)));
        hA = fmaxf(hA, 0.f);
        hB = fmaxf(hB, 0.f);

        const float4* __restrict__ row4 = (const float4*)(Wg + k * 64);
#pragma unroll
        for (int c4 = 0; c4 < 16; ++c4) {
            const float4 wv = row4[c4];
            accA[4 * c4 + 0] = fmaf(hA, wv.x, accA[4 * c4 + 0]);
            accA[4 * c4 + 1] = fmaf(hA, wv.y, accA[4 * c4 + 1]);
            accA[4 * c4 + 2] = fmaf(hA, wv.z, accA[4 * c4 + 2]);
            accA[4 * c4 + 3] = fmaf(hA, wv.w, accA[4 * c4 + 3]);
            accB[4 * c4 + 0] = fmaf(hB, wv.x, accB[4 * c4 + 0]);
            accB[4 * c4 + 1] = fmaf(hB, wv.y, accB[4 * c4 + 1]);
            accB[4 * c4 + 2] = fmaf(hB, wv.z, accB[4 * c4 + 2]);
            accB[4 * c4 + 3] = fmaf(hB, wv.w, accB[4 * c4 + 3]);
        }
    }

    if (actA) {
        unsigned int o[32];
#pragma unroll
        for (int c = 0; c < 32; ++c)
            o[c] = (unsigned int)f2bf(accA[2 * c])
                 | ((unsigned int)f2bf(accA[2 * c + 1]) << 16);
        uint4* __restrict__ dp = (uint4*)(hb_g + (size_t)nA * 64);
#pragma unroll
        for (int q = 0; q < 8; ++q)
            dp[q] = make_uint4(o[4 * q], o[4 * q + 1], o[4 * q + 2], o[4 * q + 3]);
    }
    if (actB) {
        unsigned int o[32];
#pragma unroll
        for (int c = 0; c < 32; ++c)
            o[c] = (unsigned int)f2bf(accB[2 * c])
                 | ((unsigned int)f2bf(accB[2 * c + 1]) << 16);
        uint4* __restrict__ dp = (uint4*)(hb_g + (size_t)nB * 64);
#pragma unroll
        for (int q = 0; q < 8; ++q)
            dp[q] = make_uint4(o[4 * q], o[4 * q + 1], o[4 * q + 2], o[4 * q + 3]);
    }
}

// ---------------------------------------------------------------------------
// dinv: per-bucket degree count -> dinv[n] = rsqrt(deg+1)
// ---------------------------------------------------------------------------
__global__ void dinv_kernel(const int* __restrict__ bktTot,
                            const int* __restrict__ bkt,
                            float* __restrict__ dinv)
{
    __shared__ int lcnt[128];
    const int tl = threadIdx.x;
    const int b  = blockIdx.x;
    if (tl < 128) lcnt[tl] = 0;
    __syncthreads();

    const int ne = min(bktTot[b], BKT_CAP);
    const int* __restrict__ bb = bkt + (size_t)b * BKT_CAP;
    for (int i = tl; i < ne; i += 256) atomicAdd(&lcnt[bb[i] & 127], 1);
    __syncthreads();

    if (tl < 128) {
        const int n = b * 128 + tl;
        if (n < N_NODES) dinv[n] = rsqrtf((float)(lcnt[tl] + 1));
    }
}

// ---------------------------------------------------------------------------
// gather + epilogue. One block per bucket: rebuild per-node edge lists in LDS,
// then wave-per-node gather with dinv[src] folded.
// ---------------------------------------------------------------------------
__global__ void gather_final_kernel(const unsigned short* __restrict__ hb_g,
                                    const int* __restrict__ bktTot,
                                    const int* __restrict__ bkt,
                                    const float* __restrict__ dinv,
                                    const float* __restrict__ x,
                                    const float* __restrict__ W1,
                                    const float* __restrict__ b1,
                                    const float* __restrict__ bg,
                                    const float* __restrict__ gamma,
                                    const float* __restrict__ beta,
                                    float* __restrict__ out)
{
    __shared__ int sell[128 * PAD_L];     // 32 KB
    __shared__ int lcnt[128];
    const int tl = threadIdx.x;           // 512 threads = 8 waves
    const int b  = blockIdx.x;

    if (tl < 128) lcnt[tl] = 0;
    __syncthreads();

    const int ne = min(bktTot[b], BKT_CAP);
    const int* __restrict__ bb = bkt + (size_t)b * BKT_CAP;
    for (int i = tl; i < ne; i += 512) {
        const int v  = bb[i];
        const int dl = v & 127;
        const int r  = atomicAdd(&lcnt[dl], 1);
        if (r < PAD_L) sell[dl * PAD_L + r] = v >> 7;
    }
    __syncthreads();

    const int lane = tl & 63;
    const int w    = tl >> 6;
    const float w0 = W1[lane], w1 = W1[64 + lane], w2 = W1[128 + lane];
    const float bb1 = b1[lane];
    const float bgl = bg[lane];
    const float g0 = gamma[lane], g1 = gamma[64 + lane];
    const float be0 = beta[lane], be1 = beta[64 + lane];

    for (int nl = w; nl < 128; nl += 8) {
        const int n = b * 128 + nl;
        if (n >= N_NODES) break;          // only bucket 781's tail

        const int c    = lcnt[nl];
        const float di = rsqrtf((float)(c + 1));
        const int deg  = (c < PAD_L) ? c : PAD_L;
        const int* row = sell + nl * PAD_L;

        const float xx0 = x[n * 3], xx1 = x[n * 3 + 1], xx2 = x[n * 3 + 2];
        float acc = di * bf2f(hb_g[(size_t)n * 64 + lane]);   // self loop

        int j = 0;
        for (; j + 8 <= deg; j += 8) {                        // 8 gathers in flight
            const int s0 = row[j + 0], s1 = row[j + 1], s2 = row[j + 2], s3 = row[j + 3];
            const int s4 = row[j + 4], s5 = row[j + 5], s6 = row[j + 6], s7 = row[j + 7];
            const float a0 = bf2f(hb_g[(size_t)s0 * 64 + lane]);
            const float a1 = bf2f(hb_g[(size_t)s1 * 64 + lane]);
            const float a2 = bf2f(hb_g[(size_t)s2 * 64 + lane]);
            const float a3 = bf2f(hb_g[(size_t)s3 * 64 + lane]);
            const float a4 = bf2f(hb_g[(size_t)s4 * 64 + lane]);
            const float a5 = bf2f(hb_g[(size_t)s5 * 64 + lane]);
            const float a6 = bf2f(hb_g[(size_t)s6 * 64 + lane]);
            const float a7 = bf2f(hb_g[(size_t)s7 * 64 + lane]);
            const float v0 = dinv[s0], v1 = dinv[s1], v2 = dinv[s2], v3 = dinv[s3];
            const float v4 = dinv[s4], v5 = dinv[s5], v6 = dinv[s6], v7 = dinv[s7];
            acc = fmaf(v0, a0, acc); acc = fmaf(v1, a1, acc);
            acc = fmaf(v2, a2, acc); acc = fmaf(v3, a3, acc);
            acc = fmaf(v4, a4, acc); acc = fmaf(v5, a5, acc);
            acc = fmaf(v6, a6, acc); acc = fmaf(v7, a7, acc);
        }
        for (; j < deg; ++j) {
            const int s = row[j];
            acc = fmaf(dinv[s], bf2f(hb_g[(size_t)s * 64 + lane]), acc);
        }

        float h  = fmaxf(fmaf(xx0, w0, fmaf(xx1, w1, fmaf(xx2, w2, bb1))), 0.f);
        float h2 = fmaxf(fmaf(di, acc, bgl), 0.f);

        float sum = h + h2;
#pragma unroll
        for (int o = 32; o > 0; o >>= 1) sum += __shfl_xor(sum, o, 64);
        const float mu = sum * (1.0f / 128.0f);

        const float dA = h  - mu;
        const float dB = h2 - mu;
        float vs = dA * dA + dB * dB;
#pragma unroll
        for (int o = 32; o > 0; o >>= 1) vs += __shfl_xor(vs, o, 64);
        const float rr = rsqrtf(vs * (1.0f / 128.0f) + EPS_);

        out[(size_t)n * 128 + lane]      = dA * rr * g0 + be0;
        out[(size_t)n * 128 + 64 + lane] = dB * rr * g1 + be1;
    }
}

// ---------------------------------------------------------------------------
extern "C" void kernel_launch(void* const* d_in, const int* in_sizes, int n_in,
                              void* d_out, int out_size, void* d_ws, size_t ws_size,
                              hipStream_t stream)
{
    const float* x     = (const float*)d_in[0];
    const int*   edge  = (const int*)  d_in[1];   // [2, E]: row0 = src, row1 = dst
    const float* W1    = (const float*)d_in[2];
    const float* b1    = (const float*)d_in[3];
    const float* Wg    = (const float*)d_in[4];
    const float* bg    = (const float*)d_in[5];
    const float* gamma = (const float*)d_in[6];
    const float* beta  = (const float*)d_in[7];
    float*       out   = (float*)d_out;

    // Workspace (~24.3 MB): hb_g | bkt | blkHist | bktTot | dinv
    char*  ws  = (char*)d_ws;
    size_t p   = 0;
    unsigned short* hb_g = (unsigned short*)(ws + p); p += (size_t)N_NODES * 64 * sizeof(unsigned short);
    int*            bkt  = (int*)           (ws + p); p += (size_t)NBKT * BKT_CAP * sizeof(int);
    int*         blkHist = (int*)           (ws + p); p += (size_t)NB_SORT * NBKT * sizeof(int);
    int*          bktTot = (int*)           (ws + p); p += (size_t)((NBKT * sizeof(int) + 15) & ~15);
    float*          dinv = (float*)         (ws + p);

    const int* src = edge;
    const int* dst = edge + N_EDGES;

    hist_kernel   <<<NB_SORT, 256, 0, stream>>>(dst, blkHist);
    scan_kernel   <<<NBKT,    256, 0, stream>>>(blkHist, bktTot);
    scatter_kernel<<<NB_SORT, 256, 0, stream>>>(src, dst, blkHist, bkt);
    lin_kernel    <<<NB_LIN,  128, 0, stream>>>(x, W1, b1, Wg, hb_g);
    dinv_kernel   <<<NBKT,    256, 0, stream>>>(bktTot, bkt, dinv);
    gather_final_kernel<<<NBKT, 512, 0, stream>>>(hb_g, bktTot, bkt, dinv,
                                                  x, W1, b1, bg, gamma, beta, out);
}

// Round 6
// 265.970 us; speedup vs baseline: 1.1125x; 1.1125x over previous
//
#include <hip/hip_runtime.h>
#include <math.h>

#define N_NODES 100000
#define N_EDGES 1600000
#define EPS_    1e-5f
#define PAD     64          // ELL row capacity; P(Poisson(16) > 64) ~ 1e-20
#define SCOL    48          // staged ELL columns; P(deg > 48) ~ 1e-12/node

#define NB_BUILD 6250       // E/256 exactly: one edge per thread
#define LIN_CHUNKS 1563     // 64 nodes per lin wave, lane = node

// R14: recombination of measured-best pieces.
//  - build: R10 fused atomic-ELL + reg-lin (127us measured x3; every sort
//    variant (R12 98-blk: ~160us, R13 3-pass: ~180us) was slower).
//  - scale: prescale hb_g by dinv (6us) -> gather loses 1.6M random dinv loads.
//  - gather: R12 inner loop, but 256-thr/64-node blocks (1563 blocks, 12.4KB
//    LDS -> up to 8 blk/CU vs R12's 782x512 @ 3.05 blk/CU, 35% occ) and a
//    branch-free coalesced ELL->LDS stage instead of the atomic rank-rebuild.

// ---- bf16 helpers (raw ushort storage, RNE on pack) -----------------------
__device__ __forceinline__ float bf2f(unsigned short u) {
    union { unsigned int i; float f; } v; v.i = (unsigned int)u << 16; return v.f;
}
__device__ __forceinline__ unsigned short f2bf(float f) {
    union { float f; unsigned int i; } v; v.f = f;
    unsigned int b = v.i + 0x7FFFu + ((v.i >> 16) & 1u);   // round-to-nearest-even
    return (unsigned short)(b >> 16);
}

// ---------------------------------------------------------------------------
// Kernel 1: merged ELL build + lin (R10 verbatim).
// Phase A: one edge per thread: atomicAdd(cnt[dst]) + scattered ell store.
// Phase B: lane = node; weights via wave-uniform scalar broadcasts; acc[64]
// in VGPRs. hb_g stored UNSCALED (cnt not final yet).
// ---------------------------------------------------------------------------
__global__ void build_lin_kernel(const int* __restrict__ src,
                                 const int* __restrict__ dst,
                                 const float* __restrict__ x,
                                 const float* __restrict__ W1,
                                 const float* __restrict__ b1,
                                 const float* __restrict__ Wg,
                                 int* __restrict__ cnt,
                                 int* __restrict__ ell,
                                 unsigned short* __restrict__ hb_g)
{
    const int tl   = threadIdx.x;
    const int gtid = blockIdx.x * 256 + tl;      // grid covers E exactly

    // ---- Phase A: issue edge atomic (return consumed after Phase B) ------
    const int d   = dst[gtid];
    const int s   = src[gtid];
    const int pos = atomicAdd(&cnt[d], 1);

    // ---- Phase B: lin chunk, lane = node ---------------------------------
    const int chunk = blockIdx.x * 4 + (tl >> 6);
    if (chunk < LIN_CHUNKS) {
        const int lane = tl & 63;
        const int n    = chunk * 64 + lane;
        const bool act = (n < N_NODES);
        float x0 = 0.f, x1 = 0.f, x2 = 0.f;
        if (act) { x0 = x[n * 3]; x1 = x[n * 3 + 1]; x2 = x[n * 3 + 2]; }

        float acc[64];
#pragma unroll
        for (int c = 0; c < 64; ++c) acc[c] = 0.f;

#pragma unroll 2
        for (int k = 0; k < 64; ++k) {
            const float w0 = W1[k];              // wave-uniform -> s_load
            const float w1 = W1[64 + k];
            const float w2 = W1[128 + k];
            const float bb = b1[k];
            float hk = fmaf(x0, w0, fmaf(x1, w1, fmaf(x2, w2, bb)));
            hk = fmaxf(hk, 0.f);
            const float* __restrict__ wr = Wg + k * 64;   // uniform row
#pragma unroll
            for (int c = 0; c < 64; ++c) acc[c] = fmaf(hk, wr[c], acc[c]);
        }

        if (act) {
            unsigned int o[32];
#pragma unroll
            for (int c = 0; c < 32; ++c)
                o[c] = (unsigned int)f2bf(acc[2 * c])
                     | ((unsigned int)f2bf(acc[2 * c + 1]) << 16);
            uint4* __restrict__ dp = (uint4*)(hb_g + (size_t)n * 64);
#pragma unroll
            for (int q = 0; q < 8; ++q)
                dp[q] = make_uint4(o[4 * q], o[4 * q + 1], o[4 * q + 2], o[4 * q + 3]);
        }
    }

    // ---- Phase A completion: scattered ell store -------------------------
    if (pos < PAD) ell[d * PAD + pos] = s;
}

// ---------------------------------------------------------------------------
// Kernel 2: hb_g[n][c] *= rsqrt(cnt[n]+1)  (in place, dword grain, ~6 us)
// ---------------------------------------------------------------------------
__global__ void scale_kernel(const int* __restrict__ cnt,
                             unsigned int* __restrict__ g2)
{
    const int t = blockIdx.x * blockDim.x + threadIdx.x;
    if (t >= N_NODES * 32) return;
    const int node = t >> 5;
    const float di = rsqrtf((float)(cnt[node] + 1));
    const unsigned int v = g2[t];
    const float lo = bf2f((unsigned short)(v & 0xFFFFu)) * di;
    const float hi = bf2f((unsigned short)(v >> 16)) * di;
    g2[t] = (unsigned int)f2bf(lo) | ((unsigned int)f2bf(hi) << 16);
}

// ---------------------------------------------------------------------------
// Kernel 3: gather + epilogue. 256 threads = 4 waves per block, 64 nodes per
// block. Branch-free coalesced stage of 48 ELL cols + cnt into LDS, then
// wave-per-node gather (prescaled hb_g: no dinv loads).
//   acc = hgs[n] + sum_j hgs[src_j];  h = relu(x.W1+b1)
//   h2  = relu(dinv[n]*acc + bg);  out = LayerNorm128([h,h2])*gamma + beta
// ---------------------------------------------------------------------------
__global__ void gather_final_kernel(const unsigned short* __restrict__ hb_g,
                                    const int* __restrict__ cnt,
                                    const int* __restrict__ ell,
                                    const float* __restrict__ x,
                                    const float* __restrict__ W1,
                                    const float* __restrict__ b1,
                                    const float* __restrict__ bg,
                                    const float* __restrict__ gamma,
                                    const float* __restrict__ beta,
                                    float* __restrict__ out)
{
    __shared__ int sell[64 * SCOL];       // 12 KB
    __shared__ int lcnt[64];
    const int tl = threadIdx.x;           // 256 threads = 4 waves
    const int b  = blockIdx.x;
    const int nb = b * 64;

    // ---- stage: cnt -> lcnt, 48 ELL cols -> sell (3 int4 per thread) -----
    if (tl < 64) {
        const int n = nb + tl;
        lcnt[tl] = (n < N_NODES) ? cnt[n] : 0;
    }
    {
        const int r = tl >> 2;            // row 0..63
        const int q = tl & 3;             // quad 0..3
        const int nr = nb + r;
        if (nr < N_NODES) {
            const int4* __restrict__ grow = (const int4*)(ell + (size_t)nr * PAD);
            int4* __restrict__ srow = (int4*)(sell + r * SCOL);
            srow[q]     = grow[q];        // cols  0..15
            srow[q + 4] = grow[q + 4];    // cols 16..31
            srow[q + 8] = grow[q + 8];    // cols 32..47
        }
    }
    __syncthreads();

    const int lane = tl & 63;
    const int w    = tl >> 6;
    const float w0 = W1[lane], w1 = W1[64 + lane], w2 = W1[128 + lane];
    const float bb1 = b1[lane];
    const float bgl = bg[lane];
    const float g0 = gamma[lane], g1 = gamma[64 + lane];
    const float be0 = beta[lane], be1 = beta[64 + lane];

    for (int nl = w; nl < 64; nl += 4) {
        const int n = nb + nl;
        if (n >= N_NODES) break;          // only the last block's tail

        const int c    = lcnt[nl];
        const float di = rsqrtf((float)(c + 1));
        const int deg  = (c < PAD) ? c : PAD;
        const int dstg = (deg < SCOL) ? deg : SCOL;
        const int* row = sell + nl * SCOL;

        const float xx0 = x[n * 3], xx1 = x[n * 3 + 1], xx2 = x[n * 3 + 2];
        float acc = bf2f(hb_g[(size_t)n * 64 + lane]);       // self (prescaled)

        int j = 0;
        for (; j + 8 <= dstg; j += 8) {                      // 8 gathers in flight
            const int s0 = row[j + 0], s1 = row[j + 1], s2 = row[j + 2], s3 = row[j + 3];
            const int s4 = row[j + 4], s5 = row[j + 5], s6 = row[j + 6], s7 = row[j + 7];
            const float a0 = bf2f(hb_g[(size_t)s0 * 64 + lane]);
            const float a1 = bf2f(hb_g[(size_t)s1 * 64 + lane]);
            const float a2 = bf2f(hb_g[(size_t)s2 * 64 + lane]);
            const float a3 = bf2f(hb_g[(size_t)s3 * 64 + lane]);
            const float a4 = bf2f(hb_g[(size_t)s4 * 64 + lane]);
            const float a5 = bf2f(hb_g[(size_t)s5 * 64 + lane]);
            const float a6 = bf2f(hb_g[(size_t)s6 * 64 + lane]);
            const float a7 = bf2f(hb_g[(size_t)s7 * 64 + lane]);
            acc += ((a0 + a1) + (a2 + a3)) + ((a4 + a5) + (a6 + a7));
        }
        if (j + 4 <= dstg) {
            const int s0 = row[j + 0], s1 = row[j + 1], s2 = row[j + 2], s3 = row[j + 3];
            acc += (bf2f(hb_g[(size_t)s0 * 64 + lane]) + bf2f(hb_g[(size_t)s1 * 64 + lane]))
                 + (bf2f(hb_g[(size_t)s2 * 64 + lane]) + bf2f(hb_g[(size_t)s3 * 64 + lane]));
            j += 4;
        }
        for (; j < dstg; ++j) acc += bf2f(hb_g[(size_t)row[j] * 64 + lane]);
        // astronomically-rare tail (deg > 48): read global ELL row directly
        for (; j < deg; ++j)
            acc += bf2f(hb_g[(size_t)ell[(size_t)n * PAD + j] * 64 + lane]);

        float h  = fmaxf(fmaf(xx0, w0, fmaf(xx1, w1, fmaf(xx2, w2, bb1))), 0.f);
        float h2 = fmaxf(fmaf(di, acc, bgl), 0.f);

        float sum = h + h2;
#pragma unroll
        for (int o = 32; o > 0; o >>= 1) sum += __shfl_xor(sum, o, 64);
        const float mu = sum * (1.0f / 128.0f);

        const float dA = h  - mu;
        const float dB = h2 - mu;
        float vs = dA * dA + dB * dB;
#pragma unroll
        for (int o = 32; o > 0; o >>= 1) vs += __shfl_xor(vs, o, 64);
        const float rr = rsqrtf(vs * (1.0f / 128.0f) + EPS_);

        out[(size_t)n * 128 + lane]      = dA * rr * g0 + be0;
        out[(size_t)n * 128 + 64 + lane] = dB * rr * g1 + be1;
    }
}

// ---------------------------------------------------------------------------
extern "C" void kernel_launch(void* const* d_in, const int* in_sizes, int n_in,
                              void* d_out, int out_size, void* d_ws, size_t ws_size,
                              hipStream_t stream)
{
    const float* x     = (const float*)d_in[0];
    const int*   edge  = (const int*)  d_in[1];   // [2, E]: row0 = src, row1 = dst
    const float* W1    = (const float*)d_in[2];
    const float* b1    = (const float*)d_in[3];
    const float* Wg    = (const float*)d_in[4];
    const float* bg    = (const float*)d_in[5];
    const float* gamma = (const float*)d_in[6];
    const float* beta  = (const float*)d_in[7];
    float*       out   = (float*)d_out;

    // Workspace (~38.8 MB): hb_g | ell | cnt  (16B-aligned)
    char*  ws  = (char*)d_ws;
    size_t p   = 0;
    unsigned short* hb_g = (unsigned short*)(ws + p); p += (size_t)N_NODES * 64 * sizeof(unsigned short);
    int*            ell  = (int*)           (ws + p); p += (size_t)N_NODES * PAD * sizeof(int);
    int*            cnt  = (int*)           (ws + p);

    const int* src = edge;
    const int* dst = edge + N_EDGES;

    hipMemsetAsync(cnt, 0, (size_t)N_NODES * sizeof(int), stream);

    build_lin_kernel<<<NB_BUILD, 256, 0, stream>>>(src, dst, x, W1, b1, Wg,
                                                   cnt, ell, hb_g);
    scale_kernel<<<(N_NODES * 32 + 255) / 256, 256, 0, stream>>>(cnt, (unsigned int*)hb_g);
    gather_final_kernel<<<(N_NODES + 63) / 64, 256, 0, stream>>>(hb_g, cnt, ell,
                                                                 x, W1, b1,
                                                                 bg, gamma, beta, out);
}